// Round 2
// baseline (733.411 us; speedup 1.0000x reference)
//
#include <hip/hip_runtime.h>
#include <cstdint>
#include <cstddef>

// Problem constants
#define B_DIM  8192
#define H_DIM  2048
#define LDA    6144      // A buffer column stride: [h | x | rh]
#define LDB    4096      // B buffers column stride (K=4096 concatenated)
#define NKT    64        // K tiles: K=4096 / BK=64

typedef __attribute__((ext_vector_type(8))) short  short8;   // 8 x bf16
typedef __attribute__((ext_vector_type(4))) float  float4v;  // MFMA accumulator

__device__ __forceinline__ unsigned short f2bf(float f) {
    union { float f; unsigned u; } v; v.f = f;
    unsigned r = v.u + 0x7fffu + ((v.u >> 16) & 1u);  // RNE
    return (unsigned short)(r >> 16);
}

__device__ __forceinline__ float sigmoidf_(float x) {
    return 1.0f / (1.0f + __expf(-x));
}

#define AS1CV(p) ((const __attribute__((address_space(1))) void*)(p))
#define AS3V(p)  ((__attribute__((address_space(3))) void*)(p))

// ---------------------------------------------------------------------------
// fp32 -> bf16 conversion of x_t / h_prev into the fused A buffer.
// ---------------------------------------------------------------------------
__global__ void cvt_rows(const float* __restrict__ x, const float* __restrict__ h,
                         unsigned short* __restrict__ Abuf) {
    const float* s = blockIdx.z ? h : x;
    const int coff = blockIdx.z ? 0 : 2048;
    const int row = blockIdx.x;
    const int c = threadIdx.x * 8;
    float4 a = *(const float4*)(s + (size_t)row * 2048 + c);
    float4 b = *(const float4*)(s + (size_t)row * 2048 + c + 4);
    union { unsigned short us[8]; uint4 u4; } o;
    o.us[0] = f2bf(a.x); o.us[1] = f2bf(a.y); o.us[2] = f2bf(a.z); o.us[3] = f2bf(a.w);
    o.us[4] = f2bf(b.x); o.us[5] = f2bf(b.y); o.us[6] = f2bf(b.z); o.us[7] = f2bf(b.w);
    *(uint4*)(Abuf + (size_t)row * LDA + coff + c) = o.u4;
}

// ---------------------------------------------------------------------------
// Transpose + convert: src fp32 [2048 k][2048 n] -> dst bf16 [n][k].
// ---------------------------------------------------------------------------
struct P6 { const float* s[6]; unsigned short* d[6]; };

__global__ void transpose_cvt(P6 io) {
    __shared__ float tile[64][65];
    const float* src = io.s[blockIdx.z];
    unsigned short* dst = io.d[blockIdx.z];
    const int n0 = blockIdx.x * 64;
    const int k0 = blockIdx.y * 64;
    const int t = threadIdx.x;
#pragma unroll
    for (int p = 0; p < 4; ++p) {
        const int k = p * 16 + (t >> 4);
        const int n4 = (t & 15) * 4;
        float4 v = *(const float4*)(src + (size_t)(k0 + k) * 2048 + n0 + n4);
        tile[n4 + 0][k] = v.x; tile[n4 + 1][k] = v.y;
        tile[n4 + 2][k] = v.z; tile[n4 + 3][k] = v.w;
    }
    __syncthreads();
#pragma unroll
    for (int p = 0; p < 2; ++p) {
        const int n = p * 32 + (t >> 3);
        const int k8 = (t & 7) * 8;
        union { unsigned short us[8]; uint4 u4; } o;
#pragma unroll
        for (int q = 0; q < 8; ++q) o.us[q] = f2bf(tile[n][k8 + q]);
        *(uint4*)(dst + (size_t)(n0 + n) * LDB + k0 + k8) = o.u4;
    }
}

// ---------------------------------------------------------------------------
// 256x256 8-phase GEMM core (BK=64, 8 waves 2Mx4N, 128 KiB dynamic LDS).
// LDS map (bytes): buf*65536 + isB*32768 + kh*16384 + [q 0..127][slot 0..7]*16
//   slot' = ((row&1)*4 + seg) ^ (q&7)   (XOR swizzle; conflict-free, verified
//   round 1: SQ_LDS_BANK_CONFLICT == 0).
// Round-2 schedule: register-prefetch one phase ahead.
//   phase p: { stage item p+6 ; ds_read frags for phase p+1 into alt regs ;
//              16 MFMA on regs read at p-1 ; s_waitcnt vmcnt(6) ; s_barrier }
// Gate math (items = half-tiles, 2 loads each, stream [A.Kh0,B.Kh0,A.Kh1,B.Kh1]):
//   end of phase p: issued items <= p+6, vmcnt(6) -> items <= p+3 landed.
//   reads at phase p+1 (for phase p+2) need items <= p+3.  EXACT.  Anti-dep:
//   stage(p+6) overwrites region whose last ds_read issued at phase <= p-2,
//   lgkm-retired and barrier-separated.  Safe.
// ---------------------------------------------------------------------------
struct Core8Ctx {
    const unsigned short* pA;   // per-thread pre-swizzled staging src
    const unsigned short* pB;
    char* lds;
    int t, aoff, wmb, wnb;
};

__device__ __forceinline__ void stage_item(const Core8Ctx& c, int item) {
    int tile = item >> 2;
    if (tile >= NKT) tile = 0;                 // dummy wrap into released regions
    const int isB = item & 1;                  // 0 A.Kh0, 1 B.Kh0, 2 A.Kh1, 3 B.Kh1
    const int kh  = (item >> 1) & 1;
    const int sb  = tile & 1;
    const unsigned short* src = (isB ? c.pB : c.pA) + tile * 64 + kh * 32;
    const size_t rstep = (size_t)128 * (isB ? LDB : LDA);   // +128 matrix rows
    char* dst = c.lds + sb * 65536 + isB * 32768 + kh * 16384 + c.t * 16;
    __builtin_amdgcn_global_load_lds(AS1CV(src),         AS3V(dst),        16, 0, 0);
    __builtin_amdgcn_global_load_lds(AS1CV(src + rstep), AS3V(dst + 8192), 16, 0, 0);
}

// MH: current phase's M-half (acc rows).  NBUF/NKK/NMH: next phase's coords
// (what we prefetch).  afc/bfc: regs for THIS phase (read last phase);
// afn/bfn: regs being filled for NEXT phase.
template<int MH, int NBUF, int NKK, int NMH>
__device__ __forceinline__ void phase2(const Core8Ctx& c, int item,
                                       short8 (&afc)[4], short8 (&afn)[4],
                                       short8 (&bfc)[4], short8 (&bfn)[4],
                                       float4v (&acc)[8][4]) {
    stage_item(c, item);                       // issue-early (T14)
    {
        const char* abn = c.lds + (NBUF * 65536 + NKK * 16384) + c.wmb + c.aoff;
#pragma unroll
        for (int i = 0; i < 4; ++i)
            afn[i] = *(const short8*)(abn + (NMH * 4 + i) * 1024);
        if constexpr (NMH == 0) {              // B frags change only when MH wraps
            const char* bbn = c.lds + (NBUF * 65536 + 32768 + NKK * 16384) + c.wnb + c.aoff;
#pragma unroll
            for (int j = 0; j < 4; ++j)
                bfn[j] = *(const short8*)(bbn + j * 1024);
        }
    }
    __builtin_amdgcn_s_setprio(1);
#pragma unroll
    for (int i = 0; i < 4; ++i)
#pragma unroll
        for (int j = 0; j < 4; ++j)
            acc[MH * 4 + i][j] = __builtin_amdgcn_mfma_f32_16x16x32_bf16(
                afc[i], bfc[j], acc[MH * 4 + i][j], 0, 0, 0);
    __builtin_amdgcn_s_setprio(0);
    asm volatile("s_waitcnt vmcnt(6)" ::: "memory");   // counted gate, every phase
    __builtin_amdgcn_s_barrier();              // single barrier per phase
}

__device__ __forceinline__ void gemm_core8(const unsigned short* __restrict__ Ag,
                                           const unsigned short* __restrict__ Bg,
                                           int m0, int n0, char* lds,
                                           float4v (&acc)[8][4]) {
    const int t    = threadIdx.x;
    const int lane = t & 63;
    const int wid  = t >> 6;
    Core8Ctx c;
    c.lds = lds; c.t = t;
    c.wmb = (wid >> 2) * 8192;                 // wm*64 q-lines
    c.wnb = (wid & 3) * 4096;                  // wn*32 q-lines
    const int fr  = lane & 15;
    const int seg = lane >> 4;
    c.aoff = (fr >> 1) * 128 + (((((fr & 1) << 2) | seg)) ^ ((fr >> 1) & 7)) * 16;
    const int sS   = (t & 7) ^ ((t >> 3) & 7); // pre-swizzled source slot
    const int rowS = 2 * (t >> 3) + (sS >> 2);
    const int colS = (sS & 3) * 8;
    c.pA = Ag + (size_t)(m0 + rowS) * LDA + colS;
    c.pB = Bg + (size_t)(n0 + rowS) * LDB + colS;

    // prologue: first 6 half-tiles of the stream; need items 0,1 landed
#pragma unroll
    for (int n = 0; n < 6; ++n) stage_item(c, n);
    asm volatile("s_waitcnt vmcnt(8)" ::: "memory");
    __builtin_amdgcn_s_barrier();

    // pre-loop register prefetch: phase 0's frags (BUF0, KK0, MH0)
    short8 afA[4], afB[4], bfA[4], bfB[4];
    {
        const char* ab = c.lds + c.wmb + c.aoff;
#pragma unroll
        for (int i = 0; i < 4; ++i) afA[i] = *(const short8*)(ab + i * 1024);
        const char* bb = c.lds + 32768 + c.wnb + c.aoff;
#pragma unroll
        for (int j = 0; j < 4; ++j) bfA[j] = *(const short8*)(bb + j * 1024);
    }

    for (int it = 0; it < NKT / 2; ++it) {
        const int s0 = 8 * it + 6;
        //      MH  next(BUF,KK,MH)   cur-regs      next-regs
        phase2<0, 0, 0, 1>(c, s0 + 0, afA, afB, bfA, bfB, acc);
        phase2<1, 0, 1, 0>(c, s0 + 1, afB, afA, bfA, bfB, acc);
        phase2<0, 0, 1, 1>(c, s0 + 2, afA, afB, bfB, bfA, acc);
        phase2<1, 1, 0, 0>(c, s0 + 3, afB, afA, bfB, bfA, acc);
        phase2<0, 1, 0, 1>(c, s0 + 4, afA, afB, bfA, bfB, acc);
        phase2<1, 1, 1, 0>(c, s0 + 5, afB, afA, bfA, bfB, acc);
        phase2<0, 1, 1, 1>(c, s0 + 6, afA, afB, bfB, bfA, acc);
        phase2<1, 0, 0, 0>(c, s0 + 7, afB, afA, bfB, bfA, acc);
    }
}

// ---------------------------------------------------------------------------
// GEMM 1: A(k-window [h|x]) @ Bzr -> z (fp32) to d_out, r*h_prev (bf16) to Arh.
// grid 512 blocks (32 M x 16 N), 512 threads, 128 KiB dynamic LDS.
// XCD map: XCD x owns an 8bm x 8bn quadrant-stripe; each dispatch wave of 32
// co-resident blocks is a 4bm x 8bn cluster (A 8MB + B 16MB hot set -> L2 reuse).
// ---------------------------------------------------------------------------
__global__ __launch_bounds__(512, 2) void gemm_zr(const unsigned short* __restrict__ Abuf,
                                                  const unsigned short* __restrict__ Bzr,
                                                  const float* __restrict__ hprev,
                                                  const float* __restrict__ bz,
                                                  const float* __restrict__ br,
                                                  float* __restrict__ zout,
                                                  unsigned short* __restrict__ Arh) {
    extern __shared__ char lds[];
    float4v acc[8][4];
#pragma unroll
    for (int i = 0; i < 8; ++i)
#pragma unroll
        for (int j = 0; j < 4; ++j)
            acc[i][j] = (float4v){0.f, 0.f, 0.f, 0.f};

    const int bid = blockIdx.x;
    const int x  = bid & 7;            // XCD (round-robin dispatch)
    const int s  = bid >> 3;           // per-XCD sequence 0..63
    const int st = s >> 5;             // co-residency wave 0/1
    const int w  = s & 31;
    const int bm = (x >> 1) * 8 + st * 4 + (w & 3);
    const int bn = (x & 1) * 8 + (w >> 2);
    const int m0 = bm * 256;
    const int n0 = bn * 256;           // 0..4095 across [z | r]

    gemm_core8(Abuf, Bzr, m0, n0, lds, acc);   // K = 4096 = [h | x]

    const int t = threadIdx.x, lane = t & 63;
    const int wm = (t >> 6) >> 2, wn = (t >> 6) & 3;
    const int col = lane & 15, rbase = (lane >> 4) * 4;
    const bool zhalf = n0 < 2048;
#pragma unroll
    for (int i = 0; i < 8; ++i)
#pragma unroll
        for (int j = 0; j < 4; ++j) {
            const int gn = n0 + wn * 64 + j * 16 + col;
            const int gm0 = m0 + wm * 128 + i * 16 + rbase;
            if (zhalf) {
                const float bias = bz[gn];
#pragma unroll
                for (int r = 0; r < 4; ++r) {
                    const size_t idx = (size_t)(gm0 + r) * H_DIM + gn;
                    zout[idx] = sigmoidf_(acc[i][j][r] + bias);
                }
            } else {
                const int gn2 = gn - 2048;
                const float bias = br[gn2];
#pragma unroll
                for (int r = 0; r < 4; ++r) {
                    const size_t idx = (size_t)(gm0 + r) * H_DIM + gn2;
                    const float rt = sigmoidf_(acc[i][j][r] + bias);
                    Arh[(size_t)(gm0 + r) * LDA + gn2] = f2bf(rt * hprev[idx]);
                }
            }
        }
}

// ---------------------------------------------------------------------------
// GEMM 2: A(k-window [x|rh]) @ Bh -> h_t = (1-z)h + z*tanh(.+bh).
// grid 256 blocks (32 M x 8 N).  XCD x owns a 4bm stripe x all 8 bn.
// ---------------------------------------------------------------------------
__global__ __launch_bounds__(512, 2) void gemm_h(const unsigned short* __restrict__ Axrh,
                                                 const unsigned short* __restrict__ Bh,
                                                 const float* __restrict__ hprev,
                                                 const float* __restrict__ bh,
                                                 float* __restrict__ out) {
    extern __shared__ char lds[];
    float4v acc[8][4];
#pragma unroll
    for (int i = 0; i < 8; ++i)
#pragma unroll
        for (int j = 0; j < 4; ++j)
            acc[i][j] = (float4v){0.f, 0.f, 0.f, 0.f};

    const int bid = blockIdx.x;
    const int x = bid & 7, s = bid >> 3;       // s in 0..31
    const int bm = x * 4 + (s & 3);
    const int bn = s >> 2;
    const int m0 = bm * 256;
    const int n0 = bn * 256;

    gemm_core8(Axrh, Bh, m0, n0, lds, acc);    // K = 4096 = [x | rh]

    const int t = threadIdx.x, lane = t & 63;
    const int wm = (t >> 6) >> 2, wn = (t >> 6) & 3;
    const int col = lane & 15, rbase = (lane >> 4) * 4;
#pragma unroll
    for (int i = 0; i < 8; ++i)
#pragma unroll
        for (int j = 0; j < 4; ++j) {
            const int gn = n0 + wn * 64 + j * 16 + col;
            const int gm0 = m0 + wm * 128 + i * 16 + rbase;
            const float bias = bh[gn];
#pragma unroll
            for (int r = 0; r < 4; ++r) {
                const size_t idx = (size_t)(gm0 + r) * H_DIM + gn;
                const float ht = tanhf(acc[i][j][r] + bias);
                const float z = out[idx];     // z staged here by gemm_zr
                const float h = hprev[idx];
                out[idx] = (1.0f - z) * h + z * ht;
            }
        }
}

// ---------------------------------------------------------------------------
// Workspace (144 MiB): A [0,96M) | Bzr [96,128M) | Bh [128,144M)
// ---------------------------------------------------------------------------
extern "C" void kernel_launch(void* const* d_in, const int* in_sizes, int n_in,
                              void* d_out, int out_size, void* d_ws, size_t ws_size,
                              hipStream_t stream) {
    const float* x  = (const float*)d_in[0];
    const float* h  = (const float*)d_in[1];
    const float* Wz = (const float*)d_in[2];
    const float* Wr = (const float*)d_in[3];
    const float* Wh = (const float*)d_in[4];
    const float* Uz = (const float*)d_in[5];
    const float* Ur = (const float*)d_in[6];
    const float* Uh = (const float*)d_in[7];
    const float* bz = (const float*)d_in[8];
    const float* br = (const float*)d_in[9];
    const float* bh = (const float*)d_in[10];
    float* out = (float*)d_out;

    char* ws = (char*)d_ws;
    unsigned short* Abuf = (unsigned short*)(ws);
    unsigned short* Bzr  = (unsigned short*)(ws + (size_t)96  * 1024 * 1024);
    unsigned short* Bh   = (unsigned short*)(ws + (size_t)128 * 1024 * 1024);

    // 128 KiB dynamic LDS opt-in (host-side attr set; not a stream op).
    (void)hipFuncSetAttribute((const void*)gemm_zr,
                              hipFuncAttributeMaxDynamicSharedMemorySize, 131072);
    (void)hipFuncSetAttribute((const void*)gemm_h,
                              hipFuncAttributeMaxDynamicSharedMemorySize, 131072);

    // 1) convert x, h into fused A buffer
    cvt_rows<<<dim3(B_DIM, 1, 2), 256, 0, stream>>>(x, h, Abuf);

    // 2) transpose+convert weights into concatenated-K B buffers
    P6 io;
    io.s[0] = Uz; io.d[0] = Bzr;
    io.s[1] = Wz; io.d[1] = Bzr + 2048;
    io.s[2] = Ur; io.d[2] = Bzr + (size_t)2048 * LDB;
    io.s[3] = Wr; io.d[3] = Bzr + (size_t)2048 * LDB + 2048;
    io.s[4] = Wh; io.d[4] = Bh;
    io.s[5] = Uh; io.d[5] = Bh + 2048;
    transpose_cvt<<<dim3(32, 32, 6), 256, 0, stream>>>(io);

    // 3) z/r GEMM: M=8192, N=4096, K=4096
    gemm_zr<<<dim3(512), dim3(512), 131072, stream>>>(Abuf, Bzr, h, bz, br, out,
                                                      Abuf + 4096 /* rh cols */);

    // 4) candidate GEMM + final gate: M=8192, N=2048, K=4096
    gemm_h<<<dim3(256), dim3(512), 131072, stream>>>(Abuf + 2048 /* [x|rh] */,
                                                     Bh, h, bh, out);
}

// Round 4
// 693.146 us; speedup vs baseline: 1.0581x; 1.0581x over previous
//
#include <hip/hip_runtime.h>
#include <cstdint>
#include <cstddef>

// Problem constants
#define B_DIM  8192
#define H_DIM  2048
#define LDA    6144      // A buffer column stride: [h | x | rh]
#define LDB    4096      // B buffers column stride (K=4096 concatenated)
#define NKT    64        // K tiles: K=4096 / BK=64

typedef __attribute__((ext_vector_type(8))) short  short8;   // 8 x bf16
typedef __attribute__((ext_vector_type(4))) float  float4v;  // MFMA accumulator

__device__ __forceinline__ unsigned short f2bf(float f) {
    union { float f; unsigned u; } v; v.f = f;
    unsigned r = v.u + 0x7fffu + ((v.u >> 16) & 1u);  // RNE
    return (unsigned short)(r >> 16);
}

__device__ __forceinline__ float sigmoidf_(float x) {
    return 1.0f / (1.0f + __expf(-x));
}

#define AS1CV(p) ((const __attribute__((address_space(1))) void*)(p))
#define AS3V(p)  ((__attribute__((address_space(3))) void*)(p))

// ---------------------------------------------------------------------------
// fp32 -> bf16 conversion of x_t / h_prev into the fused A buffer.
// ---------------------------------------------------------------------------
__global__ void cvt_rows(const float* __restrict__ x, const float* __restrict__ h,
                         unsigned short* __restrict__ Abuf) {
    const float* s = blockIdx.z ? h : x;
    const int coff = blockIdx.z ? 0 : 2048;
    const int row = blockIdx.x;
    const int c = threadIdx.x * 8;
    float4 a = *(const float4*)(s + (size_t)row * 2048 + c);
    float4 b = *(const float4*)(s + (size_t)row * 2048 + c + 4);
    union { unsigned short us[8]; uint4 u4; } o;
    o.us[0] = f2bf(a.x); o.us[1] = f2bf(a.y); o.us[2] = f2bf(a.z); o.us[3] = f2bf(a.w);
    o.us[4] = f2bf(b.x); o.us[5] = f2bf(b.y); o.us[6] = f2bf(b.z); o.us[7] = f2bf(b.w);
    *(uint4*)(Abuf + (size_t)row * LDA + coff + c) = o.u4;
}

// ---------------------------------------------------------------------------
// Transpose + convert: src fp32 [2048 k][2048 n] -> dst bf16 [n][k].
// ---------------------------------------------------------------------------
struct P6 { const float* s[6]; unsigned short* d[6]; };

__global__ void transpose_cvt(P6 io) {
    __shared__ float tile[64][65];
    const float* src = io.s[blockIdx.z];
    unsigned short* dst = io.d[blockIdx.z];
    const int n0 = blockIdx.x * 64;
    const int k0 = blockIdx.y * 64;
    const int t = threadIdx.x;
#pragma unroll
    for (int p = 0; p < 4; ++p) {
        const int k = p * 16 + (t >> 4);
        const int n4 = (t & 15) * 4;
        float4 v = *(const float4*)(src + (size_t)(k0 + k) * 2048 + n0 + n4);
        tile[n4 + 0][k] = v.x; tile[n4 + 1][k] = v.y;
        tile[n4 + 2][k] = v.z; tile[n4 + 3][k] = v.w;
    }
    __syncthreads();
#pragma unroll
    for (int p = 0; p < 2; ++p) {
        const int n = p * 32 + (t >> 3);
        const int k8 = (t & 7) * 8;
        union { unsigned short us[8]; uint4 u4; } o;
#pragma unroll
        for (int q = 0; q < 8; ++q) o.us[q] = f2bf(tile[n][k8 + q]);
        *(uint4*)(dst + (size_t)(n0 + n) * LDB + k0 + k8) = o.u4;
    }
}

// ---------------------------------------------------------------------------
// 256x256 pipelined GEMM core (BK=64, 8 waves 2Mx4N, 128 KiB dynamic LDS).
// LDS map (bytes): buf*65536 + isB*32768 + kh*16384 + [q 0..127][slot 0..7]*16
//   slot' = ((row&1)*4 + seg) ^ (q&7)   (XOR swizzle; conflict-free, verified:
//   SQ_LDS_BANK_CONFLICT == 0).
// Round-4 schedule = round-2's VERIFIED per-phase sync ledger, with the waits
// made clobber-free + counted, pinned by sched_barrier(0) (rule 18):
//   phase p: { stage item p+6 ; ds_read frags for p+1 ;
//              schedbar ; lgkmcnt(4|8) [drains p-1's frags ONLY — this
//              phase's reads stay in flight under the MFMAs] ; schedbar ;
//              16 MFMA on p's frags (read at p-1) ;
//              schedbar ; vmcnt(6) ; schedbar ; s_barrier }
// Ledger (items = half-tiles, 2 loads each; phase P consumes A-item P-MH,
// B-item P-MH+1; reads at p prefetch for p+1 -> need items <= p+2):
//   end of phase p: issued items <= p+6, vmcnt(6) -> items <= p+3 landed.
//   Reads at p+1 need items <= p+3.  EXACT.
//   WAR: stage(p+6) overwrites item p-2's region; its reads are lgkm-drained
//   by every wave at phase p-1 before the end-of-(p-1) barrier.  Safe.
//   Prologue: 6 items staged, vmcnt(8) -> items 0,1 landed (pre-loop frags).
// ---------------------------------------------------------------------------
struct Core8Ctx {
    const unsigned short* pA;   // per-thread pre-swizzled staging src
    const unsigned short* pB;
    char* lds;
    int t, aoff, wmb, wnb;
};

__device__ __forceinline__ void stage_item(const Core8Ctx& c, int item) {
    int tile = item >> 2;
    if (tile >= NKT) tile = 0;                 // dummy wrap into released regions
    const int isB = item & 1;                  // 0 A.Kh0, 1 B.Kh0, 2 A.Kh1, 3 B.Kh1
    const int kh  = (item >> 1) & 1;
    const int sb  = tile & 1;
    const unsigned short* src = (isB ? c.pB : c.pA) + tile * 64 + kh * 32;
    const size_t rstep = (size_t)128 * (isB ? LDB : LDA);   // +128 matrix rows
    char* dst = c.lds + sb * 65536 + isB * 32768 + kh * 16384 + c.t * 16;
    __builtin_amdgcn_global_load_lds(AS1CV(src),         AS3V(dst),        16, 0, 0);
    __builtin_amdgcn_global_load_lds(AS1CV(src + rstep), AS3V(dst + 8192), 16, 0, 0);
}

// MH: current phase's M-half.  NBUF/NKK/NMH: next phase's coords (prefetched).
// afc/bfc: regs for THIS phase (read last phase); afn/bfn: filled for NEXT.
template<int MH, int NBUF, int NKK, int NMH>
__device__ __forceinline__ void phase4(const Core8Ctx& c, int item,
                                       short8 (&afc)[4], short8 (&afn)[4],
                                       short8 (&bfc)[4], short8 (&bfn)[4],
                                       float4v (&acc)[8][4]) {
    // 1. staging for item p+6 (issue-early) + next-phase fragment reads
    stage_item(c, item);
    {
        const char* abn = c.lds + (NBUF * 65536 + NKK * 16384) + c.wmb + c.aoff;
#pragma unroll
        for (int i = 0; i < 4; ++i)
            afn[i] = *(const short8*)(abn + (NMH * 4 + i) * 1024);
        if constexpr (NMH == 0) {              // B frags change only when MH wraps
            const char* bbn = c.lds + (NBUF * 65536 + 32768 + NKK * 16384) + c.wnb + c.aoff;
#pragma unroll
            for (int j = 0; j < 4; ++j)
                bfn[j] = *(const short8*)(bbn + j * 1024);
        }
    }
    __builtin_amdgcn_sched_barrier(0);
    // 2. drain previous phase's frags only (this phase's reads stay in flight)
    asm volatile("s_waitcnt lgkmcnt(%0)" :: "n"(NMH == 0 ? 8 : 4));
    __builtin_amdgcn_sched_barrier(0);
    // 3. MFMA on frags read last phase
    __builtin_amdgcn_s_setprio(1);
#pragma unroll
    for (int i = 0; i < 4; ++i)
#pragma unroll
        for (int j = 0; j < 4; ++j)
            acc[MH * 4 + i][j] = __builtin_amdgcn_mfma_f32_16x16x32_bf16(
                afc[i], bfc[j], acc[MH * 4 + i][j], 0, 0, 0);
    __builtin_amdgcn_s_setprio(0);
    // 4. counted vmem gate + barrier (clobber-free, order pinned)
    __builtin_amdgcn_sched_barrier(0);
    asm volatile("s_waitcnt vmcnt(6)");
    __builtin_amdgcn_sched_barrier(0);
    __builtin_amdgcn_s_barrier();
}

__device__ __forceinline__ void gemm_core8(const unsigned short* __restrict__ Ag,
                                           const unsigned short* __restrict__ Bg,
                                           int m0, int n0, char* lds,
                                           float4v (&acc)[8][4]) {
    const int t    = threadIdx.x;
    const int lane = t & 63;
    const int wid  = t >> 6;
    Core8Ctx c;
    c.lds = lds; c.t = t;
    c.wmb = (wid >> 2) * 8192;                 // wm*64 q-lines
    c.wnb = (wid & 3) * 4096;                  // wn*32 q-lines
    const int fr  = lane & 15;
    const int seg = lane >> 4;
    c.aoff = (fr >> 1) * 128 + (((((fr & 1) << 2) | seg)) ^ ((fr >> 1) & 7)) * 16;
    const int sS   = (t & 7) ^ ((t >> 3) & 7); // pre-swizzled source slot
    const int rowS = 2 * (t >> 3) + (sS >> 2);
    const int colS = (sS & 3) * 8;
    c.pA = Ag + (size_t)(m0 + rowS) * LDA + colS;
    c.pB = Bg + (size_t)(n0 + rowS) * LDB + colS;

    // prologue: first 6 half-tiles of the stream; items 0,1 must land
#pragma unroll
    for (int n = 0; n < 6; ++n) stage_item(c, n);
    __builtin_amdgcn_sched_barrier(0);
    asm volatile("s_waitcnt vmcnt(8)");
    __builtin_amdgcn_sched_barrier(0);
    __builtin_amdgcn_s_barrier();

    // pre-loop register prefetch: phase 0's frags (BUF0, KK0, MH0)
    short8 afA[4], afB[4], bfA[4], bfB[4];
    {
        const char* ab = c.lds + c.wmb + c.aoff;
#pragma unroll
        for (int i = 0; i < 4; ++i) afA[i] = *(const short8*)(ab + i * 1024);
        const char* bb = c.lds + 32768 + c.wnb + c.aoff;
#pragma unroll
        for (int j = 0; j < 4; ++j) bfA[j] = *(const short8*)(bb + j * 1024);
    }

    for (int it = 0; it < NKT / 2; ++it) {
        const int s0 = 8 * it + 6;
        //      MH  next(BUF,KK,MH)   cur-regs      next-regs
        phase4<0, 0, 0, 1>(c, s0 + 0, afA, afB, bfA, bfB, acc);
        phase4<1, 0, 1, 0>(c, s0 + 1, afB, afA, bfA, bfB, acc);
        phase4<0, 0, 1, 1>(c, s0 + 2, afA, afB, bfB, bfA, acc);
        phase4<1, 1, 0, 0>(c, s0 + 3, afB, afA, bfB, bfA, acc);
        phase4<0, 1, 0, 1>(c, s0 + 4, afA, afB, bfA, bfB, acc);
        phase4<1, 1, 1, 0>(c, s0 + 5, afB, afA, bfA, bfB, acc);
        phase4<0, 1, 1, 1>(c, s0 + 6, afA, afB, bfB, bfA, acc);
        phase4<1, 0, 0, 0>(c, s0 + 7, afB, afA, bfB, bfA, acc);
    }
}

// ---------------------------------------------------------------------------
// GEMM 1: A(k-window [h|x]) @ Bzr -> z (fp32) to d_out, r*h_prev (bf16) to Arh.
// grid 512 blocks (32 M x 16 N), 512 threads, 128 KiB dynamic LDS.
// XCD map: XCD x owns an 8bm x 8bn quadrant-stripe (FETCH 596->233 MB, kept).
// ---------------------------------------------------------------------------
__global__ __launch_bounds__(512, 2) void gemm_zr(const unsigned short* __restrict__ Abuf,
                                                  const unsigned short* __restrict__ Bzr,
                                                  const float* __restrict__ hprev,
                                                  const float* __restrict__ bz,
                                                  const float* __restrict__ br,
                                                  float* __restrict__ zout,
                                                  unsigned short* __restrict__ Arh) {
    extern __shared__ char lds[];
    float4v acc[8][4];
#pragma unroll
    for (int i = 0; i < 8; ++i)
#pragma unroll
        for (int j = 0; j < 4; ++j)
            acc[i][j] = (float4v){0.f, 0.f, 0.f, 0.f};

    const int bid = blockIdx.x;
    const int x  = bid & 7;            // XCD (round-robin dispatch)
    const int s  = bid >> 3;           // per-XCD sequence 0..63
    const int st = s >> 5;             // co-residency wave 0/1
    const int w  = s & 31;
    const int bm = (x >> 1) * 8 + st * 4 + (w & 3);
    const int bn = (x & 1) * 8 + (w >> 2);
    const int m0 = bm * 256;
    const int n0 = bn * 256;           // 0..4095 across [z | r]

    gemm_core8(Abuf, Bzr, m0, n0, lds, acc);   // K = 4096 = [h | x]

    const int t = threadIdx.x, lane = t & 63;
    const int wm = (t >> 6) >> 2, wn = (t >> 6) & 3;
    const int col = lane & 15, rbase = (lane >> 4) * 4;
    const bool zhalf = n0 < 2048;
#pragma unroll
    for (int i = 0; i < 8; ++i)
#pragma unroll
        for (int j = 0; j < 4; ++j) {
            const int gn = n0 + wn * 64 + j * 16 + col;
            const int gm0 = m0 + wm * 128 + i * 16 + rbase;
            if (zhalf) {
                const float bias = bz[gn];
#pragma unroll
                for (int r = 0; r < 4; ++r) {
                    const size_t idx = (size_t)(gm0 + r) * H_DIM + gn;
                    zout[idx] = sigmoidf_(acc[i][j][r] + bias);
                }
            } else {
                const int gn2 = gn - 2048;
                const float bias = br[gn2];
#pragma unroll
                for (int r = 0; r < 4; ++r) {
                    const size_t idx = (size_t)(gm0 + r) * H_DIM + gn2;
                    const float rt = sigmoidf_(acc[i][j][r] + bias);
                    Arh[(size_t)(gm0 + r) * LDA + gn2] = f2bf(rt * hprev[idx]);
                }
            }
        }
}

// ---------------------------------------------------------------------------
// GEMM 2: A(k-window [x|rh]) @ Bh -> h_t = (1-z)h + z*tanh(.+bh).
// grid 256 blocks (32 M x 8 N).  XCD x owns a 4bm stripe x all 8 bn.
// ---------------------------------------------------------------------------
__global__ __launch_bounds__(512, 2) void gemm_h(const unsigned short* __restrict__ Axrh,
                                                 const unsigned short* __restrict__ Bh,
                                                 const float* __restrict__ hprev,
                                                 const float* __restrict__ bh,
                                                 float* __restrict__ out) {
    extern __shared__ char lds[];
    float4v acc[8][4];
#pragma unroll
    for (int i = 0; i < 8; ++i)
#pragma unroll
        for (int j = 0; j < 4; ++j)
            acc[i][j] = (float4v){0.f, 0.f, 0.f, 0.f};

    const int bid = blockIdx.x;
    const int x = bid & 7, s = bid >> 3;       // s in 0..31
    const int bm = x * 4 + (s & 3);
    const int bn = s >> 2;
    const int m0 = bm * 256;
    const int n0 = bn * 256;

    gemm_core8(Axrh, Bh, m0, n0, lds, acc);    // K = 4096 = [x | rh]

    const int t = threadIdx.x, lane = t & 63;
    const int wm = (t >> 6) >> 2, wn = (t >> 6) & 3;
    const int col = lane & 15, rbase = (lane >> 4) * 4;
#pragma unroll
    for (int i = 0; i < 8; ++i)
#pragma unroll
        for (int j = 0; j < 4; ++j) {
            const int gn = n0 + wn * 64 + j * 16 + col;
            const int gm0 = m0 + wm * 128 + i * 16 + rbase;
            const float bias = bh[gn];
#pragma unroll
            for (int r = 0; r < 4; ++r) {
                const size_t idx = (size_t)(gm0 + r) * H_DIM + gn;
                const float ht = tanhf(acc[i][j][r] + bias);
                const float z = out[idx];     // z staged here by gemm_zr
                const float h = hprev[idx];
                out[idx] = (1.0f - z) * h + z * ht;
            }
        }
}

// ---------------------------------------------------------------------------
// Workspace (144 MiB): A [0,96M) | Bzr [96,128M) | Bh [128,144M)
// ---------------------------------------------------------------------------
extern "C" void kernel_launch(void* const* d_in, const int* in_sizes, int n_in,
                              void* d_out, int out_size, void* d_ws, size_t ws_size,
                              hipStream_t stream) {
    const float* x  = (const float*)d_in[0];
    const float* h  = (const float*)d_in[1];
    const float* Wz = (const float*)d_in[2];
    const float* Wr = (const float*)d_in[3];
    const float* Wh = (const float*)d_in[4];
    const float* Uz = (const float*)d_in[5];
    const float* Ur = (const float*)d_in[6];
    const float* Uh = (const float*)d_in[7];
    const float* bz = (const float*)d_in[8];
    const float* br = (const float*)d_in[9];
    const float* bh = (const float*)d_in[10];
    float* out = (float*)d_out;

    char* ws = (char*)d_ws;
    unsigned short* Abuf = (unsigned short*)(ws);
    unsigned short* Bzr  = (unsigned short*)(ws + (size_t)96  * 1024 * 1024);
    unsigned short* Bh   = (unsigned short*)(ws + (size_t)128 * 1024 * 1024);

    // 128 KiB dynamic LDS opt-in (host-side attr set; not a stream op).
    (void)hipFuncSetAttribute((const void*)gemm_zr,
                              hipFuncAttributeMaxDynamicSharedMemorySize, 131072);
    (void)hipFuncSetAttribute((const void*)gemm_h,
                              hipFuncAttributeMaxDynamicSharedMemorySize, 131072);

    // 1) convert x, h into fused A buffer
    cvt_rows<<<dim3(B_DIM, 1, 2), 256, 0, stream>>>(x, h, Abuf);

    // 2) transpose+convert weights into concatenated-K B buffers
    P6 io;
    io.s[0] = Uz; io.d[0] = Bzr;
    io.s[1] = Wz; io.d[1] = Bzr + 2048;
    io.s[2] = Ur; io.d[2] = Bzr + (size_t)2048 * LDB;
    io.s[3] = Wr; io.d[3] = Bzr + (size_t)2048 * LDB + 2048;
    io.s[4] = Wh; io.d[4] = Bh;
    io.s[5] = Uh; io.d[5] = Bh + 2048;
    transpose_cvt<<<dim3(32, 32, 6), 256, 0, stream>>>(io);

    // 3) z/r GEMM: M=8192, N=4096, K=4096
    gemm_zr<<<dim3(512), dim3(512), 131072, stream>>>(Abuf, Bzr, h, bz, br, out,
                                                      Abuf + 4096 /* rh cols */);

    // 4) candidate GEMM + final gate: M=8192, N=2048, K=4096
    gemm_h<<<dim3(256), dim3(512), 131072, stream>>>(Abuf + 2048 /* [x|rh] */,
                                                     Bh, h, bh, out);
}